// Round 3
// baseline (1218.469 us; speedup 1.0000x reference)
//
#include <hip/hip_runtime.h>

// B=2, S=2048, D=1024, H=16, Khid=64.  Inputs/outputs f32; MFMA compute bf16.
typedef unsigned short u16;
typedef __attribute__((ext_vector_type(8))) short short8;   // 8 bf16 (4 VGPRs)
typedef __attribute__((ext_vector_type(8))) float float8;   // 32B
typedef __attribute__((ext_vector_type(4))) float floatx4;  // MFMA accumulator

__device__ __forceinline__ float bf2f(u16 b) { return __uint_as_float(((unsigned)b) << 16); }
__device__ __forceinline__ u16 f2bf(float f) {
    unsigned u = __float_as_uint(f);
    return (u16)((u + 0x7FFFu + ((u >> 16) & 1u)) >> 16);  // RNE
}

#define MFMA(a, b, c) __builtin_amdgcn_mfma_f32_16x16x32_bf16((a), (b), (c), 0, 0, 0)

// ---------------------------------------------------------------------------
// Per-head projection of x (f32) with W[h] ([D,64] f32, n-contiguous), +bias.
// mode 0: out[(bh*2048+s)*64+n] bf16 (K)   mode 1: out[(bh*64+n)*2048+s] bf16 (V^T)
// grid (64, 16) x 256
__global__ __launch_bounds__(256) void k_proj_head(
    const float* __restrict__ x, const float* __restrict__ w, const float* __restrict__ bias,
    u16* __restrict__ out, int mode)
{
    int mt = blockIdx.x, h = blockIdx.y;
    int tid = threadIdx.x, wave = tid >> 6, lane = tid & 63;
    int col = lane & 15, quad = lane >> 4, m0 = wave * 16;
    int rg0 = mt * 64;

    __shared__ u16 As[64 * 32];
    __shared__ u16 Bs[64 * 32];

    floatx4 acc[4];
    for (int i = 0; i < 4; i++) acc[i] = (floatx4){0.f, 0.f, 0.f, 0.f};

    int lr = tid >> 2, lc = (tid & 3) * 8;   // As staging: 64 rows x 32 cols
    int dr = tid >> 3, nc = (tid & 7) * 8;   // Bs transpose staging: 32 d x 64 n
    const float* wh = w + (size_t)h * 65536;

    for (int dk = 0; dk < 1024; dk += 32) {
        float8 av = *(const float8*)&x[(size_t)(rg0 + lr) * 1024 + dk + lc];
        short8 a8;
        #pragma unroll
        for (int j = 0; j < 8; j++) a8[j] = (short)f2bf(av[j]);
        *(short8*)&As[lr * 32 + lc] = a8;
        float8 wv = *(const float8*)&wh[(size_t)(dk + dr) * 64 + nc];
        #pragma unroll
        for (int j = 0; j < 8; j++) Bs[(nc + j) * 32 + dr] = f2bf(wv[j]);
        __syncthreads();
        short8 a = *(const short8*)&As[(m0 + col) * 32 + quad * 8];
        #pragma unroll
        for (int nt = 0; nt < 4; nt++) {
            short8 b = *(const short8*)&Bs[(nt * 16 + col) * 32 + quad * 8];
            acc[nt] = MFMA(a, b, acc[nt]);
        }
        __syncthreads();
    }
    #pragma unroll
    for (int nt = 0; nt < 4; nt++) {
        int n = nt * 16 + col;
        float bv = bias[h * 64 + n];
        #pragma unroll
        for (int r = 0; r < 4; r++) {
            int rowl = m0 + quad * 4 + r;
            int rg = rg0 + rowl;
            int bb = rg >> 11, s = rg & 2047;
            size_t bh = (size_t)(bb * 16 + h);
            float v = acc[nt][r] + bv;
            if (mode == 0) out[(bh * 2048 + s) * 64 + n] = f2bf(v);
            else           out[(bh * 64 + n) * 2048 + s] = f2bf(v);
        }
    }
}

// ---------------------------------------------------------------------------
// Scores: per (bh, 64-row s-tile): Q-tile on the fly (x*W_Q[h]+b_Q, bf16),
// S = Q K^T / 8, mask==0 -> -1e30, raw f32 scores -> sc, row max/sum-exp -> rmax/rsum.
// grid (32, 32) x 256
__global__ __launch_bounds__(256) void k_scores(
    const float* __restrict__ x, const float* __restrict__ wq, const float* __restrict__ bq,
    const u16* __restrict__ Kbuf, const int* __restrict__ mask,
    float* __restrict__ sc, float* __restrict__ rmax, float* __restrict__ rsum)
{
    int st = blockIdx.x, bh = blockIdx.y;
    int b = bh >> 4, h = bh & 15;
    int s0 = st * 64;
    int tid = threadIdx.x, wave = tid >> 6, lane = tid & 63;
    int col = lane & 15, quad = lane >> 4, m0 = wave * 16;

    __shared__ u16 As[64 * 32];
    __shared__ u16 Bs[64 * 32];
    __shared__ u16 Qs[64 * 64];
    __shared__ u16 Ks[64 * 64];
    __shared__ float Sf[64 * 64];
    __shared__ float mrun[64], lrun[64];

    // ---- Phase 1: Q tile ----
    floatx4 acc[4];
    for (int i = 0; i < 4; i++) acc[i] = (floatx4){0.f, 0.f, 0.f, 0.f};
    int lr = tid >> 2, lc = (tid & 3) * 8;
    int dr = tid >> 3, nc = (tid & 7) * 8;
    const float* wh = wq + (size_t)h * 65536;
    const float* xb = x + ((size_t)b * 2048 + s0) * 1024;

    for (int dk = 0; dk < 1024; dk += 32) {
        float8 av = *(const float8*)&xb[(size_t)lr * 1024 + dk + lc];
        short8 a8;
        #pragma unroll
        for (int j = 0; j < 8; j++) a8[j] = (short)f2bf(av[j]);
        *(short8*)&As[lr * 32 + lc] = a8;
        float8 wv = *(const float8*)&wh[(size_t)(dk + dr) * 64 + nc];
        #pragma unroll
        for (int j = 0; j < 8; j++) Bs[(nc + j) * 32 + dr] = f2bf(wv[j]);
        __syncthreads();
        short8 a = *(const short8*)&As[(m0 + col) * 32 + quad * 8];
        #pragma unroll
        for (int nt = 0; nt < 4; nt++) {
            short8 b2 = *(const short8*)&Bs[(nt * 16 + col) * 32 + quad * 8];
            acc[nt] = MFMA(a, b2, acc[nt]);
        }
        __syncthreads();
    }
    if (tid < 64) { mrun[tid] = -1e30f; lrun[tid] = 0.f; }
    #pragma unroll
    for (int nt = 0; nt < 4; nt++) {
        int n = nt * 16 + col;
        float bv = bq[h * 64 + n];
        #pragma unroll
        for (int r = 0; r < 4; r++) {
            int rowl = m0 + quad * 4 + r;
            Qs[rowl * 64 + n] = f2bf(acc[nt][r] + bv);
        }
    }
    __syncthreads();

    // ---- Phase 2: S = Q K^T / 8, mask, stats ----
    const u16* Kh = Kbuf + (size_t)bh * 2048 * 64;
    short8 aq0 = *(const short8*)&Qs[(m0 + col) * 64 + quad * 8];
    short8 aq1 = *(const short8*)&Qs[(m0 + col) * 64 + 32 + quad * 8];

    for (int t0 = 0; t0 < 2048; t0 += 64) {
        {
            int row = tid >> 3, off = (tid & 7) * 8;
            *(short8*)&Ks[row * 64 + off] = *(const short8*)&Kh[(size_t)(t0 + row) * 64 + off];
            row += 32;
            *(short8*)&Ks[row * 64 + off] = *(const short8*)&Kh[(size_t)(t0 + row) * 64 + off];
        }
        __syncthreads();
        floatx4 c4[4];
        #pragma unroll
        for (int nt = 0; nt < 4; nt++) {
            c4[nt] = (floatx4){0.f, 0.f, 0.f, 0.f};
            short8 b0 = *(const short8*)&Ks[(nt * 16 + col) * 64 + quad * 8];
            short8 b1 = *(const short8*)&Ks[(nt * 16 + col) * 64 + 32 + quad * 8];
            c4[nt] = MFMA(aq0, b0, c4[nt]);
            c4[nt] = MFMA(aq1, b1, c4[nt]);
        }
        #pragma unroll
        for (int nt = 0; nt < 4; nt++) {
            int t = t0 + nt * 16 + col;
            #pragma unroll
            for (int r = 0; r < 4; r++) {
                int rowl = m0 + quad * 4 + r;
                int s = s0 + rowl;
                int mv = mask[((size_t)b * 2048 + s) * 2048 + t];
                float v = (mv == 0) ? -1e30f : c4[nt][r] * 0.125f;
                sc[((size_t)bh * 2048 + s) * 2048 + t] = v;
                Sf[rowl * 64 + nt * 16 + col] = v;
            }
        }
        __syncthreads();
        int row = tid >> 2, seg = tid & 3;
        const float* sp = &Sf[row * 64 + seg * 16];
        float tm = -1e30f;
        for (int i = 0; i < 16; i++) tm = fmaxf(tm, sp[i]);
        tm = fmaxf(tm, __shfl_xor(tm, 1, 64));
        tm = fmaxf(tm, __shfl_xor(tm, 2, 64));
        float ts = 0.f;
        for (int i = 0; i < 16; i++) {
            float v = sp[i];
            ts += (v <= -0.9e30f) ? 0.f : __expf(v - tm);
        }
        ts += __shfl_xor(ts, 1, 64);
        ts += __shfl_xor(ts, 2, 64);
        if (seg == 0 && tm > -0.9e30f) {
            float om = mrun[row];
            float nm = fmaxf(om, tm);
            lrun[row] = lrun[row] * __expf(om - nm) + ts * __expf(tm - nm);
            mrun[row] = nm;
        }
        __syncthreads();
    }
    if (tid < 64) {
        rmax[(size_t)bh * 2048 + s0 + tid] = mrun[tid];
        rsum[(size_t)bh * 2048 + s0 + tid] = lrun[tid];
    }
}

// ---------------------------------------------------------------------------
// PV fused with normalization: read raw f32 scores, p=exp(s-m)/l, write p back
// (final attn_scores output), bf16-ize into LDS, MFMA with V^T -> concat bf16.
// Each block owns score rows [s0, s0+64) of one bh: no cross-block hazards.
// grid (32, 32) x 256
__global__ __launch_bounds__(256) void k_pv(
    float* __restrict__ sc, const u16* __restrict__ Vt,
    const float* __restrict__ rmax, const float* __restrict__ rsum,
    u16* __restrict__ concat)
{
    int mt = blockIdx.x, bh = blockIdx.y;
    int h = bh & 15, bb = bh >> 4;
    int tid = threadIdx.x, wave = tid >> 6, lane = tid & 63;
    int col = lane & 15, quad = lane >> 4, m0 = wave * 16;
    int s0 = mt * 64;

    float* P = sc + (size_t)bh * 2048 * 2048;
    const u16* Vh = Vt + (size_t)bh * 64 * 2048;

    __shared__ u16 As[64 * 32];
    __shared__ u16 Bs[64 * 32];

    floatx4 acc[4];
    for (int i = 0; i < 4; i++) acc[i] = (floatx4){0.f, 0.f, 0.f, 0.f};

    int lr = tid >> 2, lc = (tid & 3) * 8;
    float m  = rmax[(size_t)bh * 2048 + s0 + lr];
    float rl = 1.0f / rsum[(size_t)bh * 2048 + s0 + lr];

    for (int t = 0; t < 2048; t += 32) {
        float8 raw = *(const float8*)&P[(size_t)(s0 + lr) * 2048 + t + lc];
        float8 po;
        short8 a8;
        #pragma unroll
        for (int j = 0; j < 8; j++) {
            float p = __expf(raw[j] - m) * rl;
            po[j] = p;
            a8[j] = (short)f2bf(p);
        }
        *(float8*)&P[(size_t)(s0 + lr) * 2048 + t + lc] = po;   // normalized scores out
        *(short8*)&As[lr * 32 + lc] = a8;
        *(short8*)&Bs[lr * 32 + lc] = *(const short8*)&Vh[(size_t)lr * 2048 + t + lc];
        __syncthreads();
        short8 a = *(const short8*)&As[(m0 + col) * 32 + quad * 8];
        #pragma unroll
        for (int nt = 0; nt < 4; nt++) {
            short8 b = *(const short8*)&Bs[(nt * 16 + col) * 32 + quad * 8];
            acc[nt] = MFMA(a, b, acc[nt]);
        }
        __syncthreads();
    }
    #pragma unroll
    for (int nt = 0; nt < 4; nt++) {
        int n = nt * 16 + col;
        #pragma unroll
        for (int r = 0; r < 4; r++) {
            int rowl = m0 + quad * 4 + r;
            int s = s0 + rowl;
            concat[((size_t)(bb * 2048 + s)) * 1024 + h * 64 + n] = f2bf(acc[nt][r]);
        }
    }
}

// ---------------------------------------------------------------------------
// Output projection: out f32 = concat(bf16) @ W_proj(f32) + b_proj.
// grid (64, 16) x 256
__global__ __launch_bounds__(256) void k_out(
    const u16* __restrict__ concat, const float* __restrict__ wp,
    const float* __restrict__ bp, float* __restrict__ outp)
{
    int mt = blockIdx.x, ntile = blockIdx.y;
    int n0 = ntile * 64;
    int tid = threadIdx.x, wave = tid >> 6, lane = tid & 63;
    int col = lane & 15, quad = lane >> 4, m0 = wave * 16;
    int rg0 = mt * 64;

    __shared__ u16 As[64 * 32];
    __shared__ u16 Bs[64 * 32];

    floatx4 acc[4];
    for (int i = 0; i < 4; i++) acc[i] = (floatx4){0.f, 0.f, 0.f, 0.f};

    int lr = tid >> 2, lc = (tid & 3) * 8;
    int cr = tid >> 3, nc = (tid & 7) * 8;
    for (int c = 0; c < 1024; c += 32) {
        *(short8*)&As[lr * 32 + lc] = *(const short8*)&concat[(size_t)(rg0 + lr) * 1024 + c + lc];
        float8 wv = *(const float8*)&wp[(size_t)(c + cr) * 1024 + n0 + nc];
        #pragma unroll
        for (int j = 0; j < 8; j++) Bs[(nc + j) * 32 + cr] = f2bf(wv[j]);
        __syncthreads();
        short8 a = *(const short8*)&As[(m0 + col) * 32 + quad * 8];
        #pragma unroll
        for (int nt = 0; nt < 4; nt++) {
            short8 b = *(const short8*)&Bs[(nt * 16 + col) * 32 + quad * 8];
            acc[nt] = MFMA(a, b, acc[nt]);
        }
        __syncthreads();
    }
    #pragma unroll
    for (int nt = 0; nt < 4; nt++) {
        int n = n0 + nt * 16 + col;
        float bv = bp[n];
        #pragma unroll
        for (int r = 0; r < 4; r++) {
            int rowl = m0 + quad * 4 + r;
            outp[(size_t)(rg0 + rowl) * 1024 + n] = acc[nt][r] + bv;
        }
    }
}

// ---------------------------------------------------------------------------
extern "C" void kernel_launch(void* const* d_in, const int* in_sizes, int n_in,
                              void* d_out, int out_size, void* d_ws, size_t ws_size,
                              hipStream_t stream) {
    const float* x  = (const float*)d_in[0];
    const float* WQ = (const float*)d_in[1];
    const float* bQ = (const float*)d_in[2];
    const float* WK = (const float*)d_in[3];
    const float* bK = (const float*)d_in[4];
    const float* WV = (const float*)d_in[5];
    const float* bV = (const float*)d_in[6];
    const float* WP = (const float*)d_in[7];
    const float* bP = (const float*)d_in[8];
    const int* mask = (const int*)d_in[9];

    float* out = (float*)d_out;
    float* attn_out = out;                     // [2,2048,1024] f32 = 4,194,304 elems
    float* sc = out + (size_t)4194304;         // [2,16,2048,2048] f32

    const size_t NEED = (size_t)3 * 8388608 + 2 * 262144;  // K,Vt,concat bf16 + stats
    u16 *Kbuf, *Vtb, *concat;
    float *rmax, *rsum;
    if (ws_size >= NEED) {
        char* ws = (char*)d_ws;
        Kbuf   = (u16*)ws;               ws += 8388608;
        Vtb    = (u16*)ws;               ws += 8388608;
        concat = (u16*)ws;               ws += 8388608;
        rmax   = (float*)ws;             ws += 262144;
        rsum   = (float*)ws;
    } else {
        // Fallback (deterministic across calls): K|Vt overlay the dead
        // attn_out region (16.78MB, written last); stats in dead W_K buffer;
        // concat in dead mask buffer.
        Kbuf   = (u16*)attn_out;
        Vtb    = Kbuf + (size_t)4194304;
        rmax   = (float*)d_in[3];
        rsum   = rmax + 65536;
        concat = (u16*)d_in[9];
    }

    k_proj_head<<<dim3(64, 16), 256, 0, stream>>>(x, WK, bK, Kbuf, 0);     // K
    k_proj_head<<<dim3(64, 16), 256, 0, stream>>>(x, WV, bV, Vtb, 1);      // V^T
    k_scores<<<dim3(32, 32), 256, 0, stream>>>(x, WQ, bQ, Kbuf, mask, sc, rmax, rsum);
    k_pv<<<dim3(32, 32), 256, 0, stream>>>(sc, Vtb, rmax, rsum, concat);
    k_out<<<dim3(64, 16), 256, 0, stream>>>(concat, WP, bP, attn_out);
}